// Round 7
// baseline (228.471 us; speedup 1.0000x reference)
//
#include <hip/hip_runtime.h>

// NGP multiresolution hash-grid interpolation encoding.
// B=262144 points, DIM=3, L=16 levels, T=19 (2^19 entries/level), F=2.
//
// Structure (R6, kept): spatial counting-sort -> level-phased gather with
// table replicated in all 8 XCD L2s (cheap/expensive level interleave
// {0,15,1,14,...} so the ~2-level dispatch window holds 1 expensive table
// + 1 L1-resident cheap level) -> LDS transpose + un-permute (one 128B
// line per point).
// R7 changes:
//  (a) branchless x-corner pair loads: i1 = (ix+1)^hyz == i0^1 for even ix,
//      so both corners come from one aligned 16B tbl4 load; even-ix lanes'
//      second load merges at L1/MSHR -> ~25% fewer L2 requests on the
//      hash-saturated levels (the measured 16 req/cyc/L2 floor).
//  (b) lean sort: 4096 buckets, hipMemsetAsync zeroing, scan fused into
//      scatter (redundant 16KB LDS scan per block ~ free).

#define NB 262144
#define NL 16
#define TSIZE (1u << 19)
#define TMASK ((1u << 19) - 1u)
#define P1 2654435761u
#define P2 805459861u
#define NBKT 4096  // 16^3 spatial buckets

typedef float vf2 __attribute__((ext_vector_type(2)));
typedef float vf4 __attribute__((ext_vector_type(4)));

__constant__ float RES_C[NL] = {16.f, 20.f, 25.f, 32.f, 40.f, 50.f, 64.f, 80.f,
                                101.f, 128.f, 161.f, 203.f, 256.f, 322.f, 406.f, 512.f};

// cheap/expensive interleave for the ~2-level dispatch window
__constant__ int SEQ_C[NL] = {0, 15, 1, 14, 2, 13, 3, 12, 4, 11, 5, 10, 6, 9, 7, 8};

__device__ __forceinline__ int bucket_of(float px, float py, float pz) {
  int bx = min(15, (int)(px * 16.0f));
  int by = min(15, (int)(py * 16.0f));
  int bz = min(15, (int)(pz * 16.0f));
  return bx | (by << 4) | (bz << 8);
}

__device__ __forceinline__ void ngp_point_level(
    float px, float py, float pz, int l, const float* __restrict__ tables,
    float& o0, float& o1) {
  const float res = RES_C[l];
  const float sx = px * res, sy = py * res, sz = pz * res;
  const float fx = floorf(sx), fy = floorf(sy), fz = floorf(sz);
  const unsigned ix = (unsigned)fx, iy = (unsigned)fy, iz = (unsigned)fz;

  const unsigned hy0 = iy * P1, hy1 = hy0 + P1;
  const unsigned hz0 = iz * P2, hz1 = hz0 + P2;

  const float wx0 = 1.0f - fabsf(sx - fx);
  const float wx1 = 1.0f - fabsf(sx - (fx + 1.0f));
  const float wy0 = 1.0f - fabsf(sy - fy);
  const float wy1 = 1.0f - fabsf(sy - (fy + 1.0f));
  const float wz0 = 1.0f - fabsf(sz - fz);
  const float wz1 = 1.0f - fabsf(sz - (fz + 1.0f));

  const vf4* __restrict__ tbl4 = (const vf4*)tables + (size_t)l * (TSIZE / 2);

  unsigned hyz[4];  // p = ybit + 2*zbit
  hyz[0] = hy0 ^ hz0;
  hyz[1] = hy1 ^ hz0;
  hyz[2] = hy0 ^ hz1;
  hyz[3] = hy1 ^ hz1;
  float wyz[4];
  wyz[0] = wy0 * wz0; wyz[1] = wy1 * wz0; wyz[2] = wy0 * wz1; wyz[3] = wy1 * wz1;

  o0 = 0.0f; o1 = 0.0f;
#pragma unroll
  for (int p = 0; p < 4; ++p) {
    const unsigned i0 = (ix ^ hyz[p]) & TMASK;
    const unsigned i1 = ((ix + 1u) ^ hyz[p]) & TMASK;
    // 16B pair loads; for even ix, i1>>1 == i0>>1 -> the q1 load merges
    // at L1/MSHR (no extra L2 request). Branch-free.
    const vf4 q0 = tbl4[i0 >> 1];
    const vf4 q1 = tbl4[i1 >> 1];
    const float g0x = (i0 & 1u) ? q0.z : q0.x;
    const float g0y = (i0 & 1u) ? q0.w : q0.y;
    const float g1x = (i1 & 1u) ? q1.z : q1.x;
    const float g1y = (i1 & 1u) ? q1.w : q1.y;
    const float w0 = wx0 * wyz[p];
    const float w1 = wx1 * wyz[p];
    o0 = fmaf(w1, g1x, fmaf(w0, g0x, o0));
    o1 = fmaf(w1, g1y, fmaf(w0, g0y, o1));
  }
}

// ---- sort phase ----
__global__ __launch_bounds__(256) void hist_kernel(
    const float* __restrict__ x, unsigned* __restrict__ hist) {
  const int b = blockIdx.x * 256 + threadIdx.x;
  const float px = x[b * 3 + 0], py = x[b * 3 + 1], pz = x[b * 3 + 2];
  atomicAdd(&hist[bucket_of(px, py, pz)], 1u);
}

// scatter with fused (redundant per-block) scan of the 4096-entry histogram
__global__ __launch_bounds__(256) void scatter_kernel(
    const float* __restrict__ x, const unsigned* __restrict__ hist,
    unsigned* __restrict__ cnt, vf4* __restrict__ xp) {
  __shared__ unsigned soff[NBKT];
  __shared__ unsigned part[256];
  const int t = threadIdx.x;
  const int base = t * (NBKT / 256);  // 16 buckets per thread

  unsigned loc[NBKT / 256];
  unsigned s = 0;
#pragma unroll
  for (int i = 0; i < NBKT / 256; ++i) { loc[i] = s; s += hist[base + i]; }
  part[t] = s;
  __syncthreads();
  for (int d = 1; d < 256; d <<= 1) {
    unsigned v = (t >= d) ? part[t - d] : 0u;
    __syncthreads();
    part[t] += v;
    __syncthreads();
  }
  const unsigned pre = (t == 0) ? 0u : part[t - 1];
#pragma unroll
  for (int i = 0; i < NBKT / 256; ++i) soff[base + i] = pre + loc[i];
  __syncthreads();

  const int b = blockIdx.x * 256 + t;
  const float px = x[b * 3 + 0], py = x[b * 3 + 1], pz = x[b * 3 + 2];
  const int bkt = bucket_of(px, py, pz);
  const unsigned rank = atomicAdd(&cnt[bkt], 1u);
  const unsigned pos = soff[bkt] + rank;
  vf4 v; v.x = px; v.y = py; v.z = pz; v.w = __uint_as_float((unsigned)b);
  xp[pos] = v;
}

// ---- phase 1: level-phased gather over sorted points ----
__global__ __launch_bounds__(256) void ngp_gather_sorted_kernel(
    const vf4* __restrict__ xp,        // (B,) sorted: x,y,z,orig_id
    const float* __restrict__ tables,  // (L, 2^19, 2)
    vf2* __restrict__ ws) {            // (L, B) in sorted order
  const int i = blockIdx.x;        // 0..16383
  const int lvl = SEQ_C[i >> 10];  // level-major phases
  const int chunk = i & 1023;
  const int p = chunk * 256 + threadIdx.x;

  const vf4 v = __builtin_nontemporal_load(xp + p);

  float o0, o1;
  ngp_point_level(v.x, v.y, v.z, lvl, tables, o0, o1);

  vf2 r; r.x = o0; r.y = o1;
  __builtin_nontemporal_store(r, ws + (size_t)lvl * NB + p);
}

// ---- phase 2: transpose + un-permute. Each point's out row = one 128B line. ----
__global__ __launch_bounds__(256) void ngp_transpose_sorted_kernel(
    const vf2* __restrict__ ws,   // (L, B) sorted order
    const vf4* __restrict__ xp,   // orig_id in .w
    vf4* __restrict__ out4) {     // (B, 8) float4 rows, original order
  __shared__ vf2 tile[NL][257];
  __shared__ unsigned pid[256];
  const int t = threadIdx.x;
  const int p0 = blockIdx.x * 256;

#pragma unroll
  for (int l = 0; l < NL; ++l) {
    tile[l][t] = __builtin_nontemporal_load(ws + (size_t)l * NB + p0 + t);
  }
  pid[t] = __float_as_uint(xp[p0 + t].w);
  __syncthreads();

#pragma unroll
  for (int k = 0; k < 8; ++k) {
    const int q = k * 256 + t;
    const int pq = q >> 3;
    const int wq = q & 7;
    const vf2 a = tile[2 * wq + 0][pq];
    const vf2 c = tile[2 * wq + 1][pq];
    vf4 v; v.x = a.x; v.y = a.y; v.z = c.x; v.w = c.y;
    out4[(size_t)pid[pq] * 8 + wq] = v;
  }
}

// ---- R3 path (no sort) if ws is small ----
__global__ __launch_bounds__(256) void ngp_gather_kernel(
    const float* __restrict__ x, const float* __restrict__ tables,
    vf2* __restrict__ ws) {
  const int i = blockIdx.x;
  const int lvl = (i & 7) | ((i >> 13) << 3);
  const int chunk = (i >> 3) & 1023;
  const int b = chunk * 256 + threadIdx.x;
  const float px = __builtin_nontemporal_load(x + b * 3 + 0);
  const float py = __builtin_nontemporal_load(x + b * 3 + 1);
  const float pz = __builtin_nontemporal_load(x + b * 3 + 2);
  float o0, o1;
  ngp_point_level(px, py, pz, lvl, tables, o0, o1);
  vf2 r; r.x = o0; r.y = o1;
  __builtin_nontemporal_store(r, ws + (size_t)lvl * NB + b);
}

__global__ __launch_bounds__(256) void ngp_transpose_kernel(
    const vf2* __restrict__ ws, vf4* __restrict__ out4) {
  __shared__ vf2 tile[NL][257];
  const int t = threadIdx.x;
  const int p0 = blockIdx.x * 256;
#pragma unroll
  for (int l = 0; l < NL; ++l) {
    tile[l][t] = __builtin_nontemporal_load(ws + (size_t)l * NB + p0 + t);
  }
  __syncthreads();
#pragma unroll
  for (int k = 0; k < 8; ++k) {
    const int q = k * 256 + t;
    const int pq = q >> 3;
    const int wq = q & 7;
    const vf2 a = tile[2 * wq + 0][pq];
    const vf2 c = tile[2 * wq + 1][pq];
    vf4 v; v.x = a.x; v.y = a.y; v.z = c.x; v.w = c.y;
    __builtin_nontemporal_store(v, out4 + (size_t)p0 * 8 + q);
  }
}

// ---- last-resort fused fallback ----
__global__ __launch_bounds__(256) void ngp_fused_kernel(
    const float* __restrict__ x, const float* __restrict__ tables,
    float* __restrict__ out) {
  const int tid = blockIdx.x * blockDim.x + threadIdx.x;
  const int l = tid & (NL - 1);
  const int b = tid >> 4;
  float o0, o1;
  ngp_point_level(x[b * 3], x[b * 3 + 1], x[b * 3 + 2], l, tables, o0, o1);
  float2 r = make_float2(o0, o1);
  ((float2*)out)[tid] = r;
}

extern "C" void kernel_launch(void* const* d_in, const int* in_sizes, int n_in,
                              void* d_out, int out_size, void* d_ws, size_t ws_size,
                              hipStream_t stream) {
  const float* x = (const float*)d_in[0];
  const float* tables = (const float*)d_in[1];
  float* out = (float*)d_out;

  const size_t ws2_b = (size_t)NL * NB * sizeof(vf2);     // 32 MB
  const size_t xp_b = (size_t)NB * sizeof(vf4);           // 4 MB
  const size_t hist_b = (size_t)NBKT * sizeof(unsigned);  // 16 KB
  const size_t sorted_need = ws2_b + xp_b + 2 * hist_b;

  if (ws_size >= sorted_need) {
    char* base = (char*)d_ws;
    vf2* ws2 = (vf2*)base;
    vf4* xp = (vf4*)(base + ws2_b);
    unsigned* hist = (unsigned*)(base + ws2_b + xp_b);
    unsigned* cnt = (unsigned*)(base + ws2_b + xp_b + hist_b);

    hipMemsetAsync(hist, 0, 2 * hist_b, stream);  // zeroes hist + cnt
    hist_kernel<<<NB / 256, 256, 0, stream>>>(x, hist);
    scatter_kernel<<<NB / 256, 256, 0, stream>>>(x, hist, cnt, xp);
    ngp_gather_sorted_kernel<<<NB * NL / 256, 256, 0, stream>>>(xp, tables, ws2);
    ngp_transpose_sorted_kernel<<<NB / 256, 256, 0, stream>>>(ws2, xp, (vf4*)out);
  } else if (ws_size >= ws2_b) {
    vf2* ws = (vf2*)d_ws;
    ngp_gather_kernel<<<NB * NL / 256, 256, 0, stream>>>(x, tables, ws);
    ngp_transpose_kernel<<<NB / 256, 256, 0, stream>>>(ws, (vf4*)out);
  } else {
    ngp_fused_kernel<<<NB * NL / 256, 256, 0, stream>>>(x, tables, out);
  }
}